// Round 5
// baseline (849.863 us; speedup 1.0000x reference)
//
#include <hip/hip_runtime.h>
#include <cstdint>
#include <cstddef>

#define NNODES 20000
#define NEDGES 320000
#define NBATCH 64
#define EPRIME (NEDGES + NNODES)

// ---------------------------------------------------------------- CSR build
__global__ __launch_bounds__(256) void count_kernel(const int* __restrict__ ei,
                                                    int* __restrict__ cnt) {
    int k = blockIdx.x * 256 + threadIdx.x;
    if (k >= EPRIME) return;
    int dst = (k < NEDGES) ? ei[NEDGES + k] : (k - NEDGES);
    atomicAdd(&cnt[dst], 1);
}

// Register-blocked exclusive scan: 1 block x 1024 threads x 20 elems/thread.
__global__ __launch_bounds__(1024) void scan_kernel(const int* __restrict__ cnt,
                                                    int* __restrict__ row_ptr,
                                                    int* __restrict__ fillp) {
    constexpr int CHUNK = 20;              // 1024*20 = 20480 >= NNODES
    int t = threadIdx.x;
    int base = t * CHUNK;
    int v[CHUNK];
    int sum = 0;
#pragma unroll
    for (int i = 0; i < CHUNK; i++) {
        int idx = base + i;
        v[i] = (idx < NNODES) ? cnt[idx] : 0;
        sum += v[i];
    }
    int lane = t & 63, wid = t >> 6;       // 16 waves
    int s = sum;
    for (int off = 1; off < 64; off <<= 1) {
        int x = __shfl_up(s, off);
        if (lane >= off) s += x;
    }
    __shared__ int wsum[16];
    __shared__ int woff[17];
    if (lane == 63) wsum[wid] = s;
    __syncthreads();
    if (t == 0) {
        int acc = 0;
        for (int i = 0; i < 16; i++) { woff[i] = acc; acc += wsum[i]; }
        woff[16] = acc;
    }
    __syncthreads();
    int excl = woff[wid] + s - sum;        // exclusive prefix at chunk start
#pragma unroll
    for (int i = 0; i < CHUNK; i++) {
        int idx = base + i;
        if (idx < NNODES) { row_ptr[idx] = excl; fillp[idx] = excl; }
        excl += v[i];
    }
    if (t == 0) row_ptr[NNODES] = woff[16];
}

__global__ __launch_bounds__(256) void fill_kernel(const int* __restrict__ ei,
                                                   int* __restrict__ fillp,
                                                   int* __restrict__ csr_src) {
    int k = blockIdx.x * 256 + threadIdx.x;
    if (k >= EPRIME) return;
    int src, dst;
    if (k < NEDGES) { src = ei[k]; dst = ei[NEDGES + k]; }
    else            { src = k - NEDGES; dst = src; }
    int pos = atomicAdd(&fillp[dst], 1);
    csr_src[pos] = src;
}

#define FMA16(ACC, AV, BV)                                        \
    ACC[0][0] += AV.x * BV.x; ACC[0][1] += AV.x * BV.y;           \
    ACC[0][2] += AV.x * BV.z; ACC[0][3] += AV.x * BV.w;           \
    ACC[1][0] += AV.y * BV.x; ACC[1][1] += AV.y * BV.y;           \
    ACC[1][2] += AV.y * BV.z; ACC[1][3] += AV.y * BV.w;           \
    ACC[2][0] += AV.z * BV.x; ACC[2][1] += AV.z * BV.y;           \
    ACC[2][2] += AV.z * BV.z; ACC[2][3] += AV.z * BV.w;           \
    ACC[3][0] += AV.w * BV.x; ACC[3][1] += AV.w * BV.y;           \
    ACC[3][2] += AV.w * BV.z; ACC[3][3] += AV.w * BV.w;

// ---------------------------------------------------------------- fp32 GEMM 128x128 (N=256 layers)
// C[M,256] = A[M,K] @ B[K,256]. BK=16, 256 threads, 8x8/thread as 2x2 sub-tiles.
// 64 FMA : 4 ds_read_b128 per kk -> VALU-dominant. N-tile covers 2 heads;
// fused score epilogue: head = 2*blockIdx.y + colhalf.
__global__ __launch_bounds__(256) void gemm128_kernel(const float* __restrict__ A,
                                                      const float* __restrict__ B,
                                                      float* __restrict__ C,
                                                      int M, int K,
                                                      const float* __restrict__ a_src,
                                                      const float* __restrict__ a_dst,
                                                      float* __restrict__ s_sc,
                                                      float* __restrict__ d_sc) {
    constexpr int Nn = 256;
    constexpr int H  = 4;
    __shared__ float As[16][129];   // transposed, padded
    __shared__ float Bs[16][128];
    int t  = threadIdx.x;
    int bm = blockIdx.x * 128;
    int bn = blockIdx.y * 128;
    int tx = t % 16, ty = t / 16;
    float acc[2][2][4][4] = {};     // [rowhalf][colhalf][i][j]

    int ar = t >> 2;                // 0..63  (A row within tile)
    int ak = (t & 3) * 4;           // 0,4,8,12
    int br = t >> 5;                // 0..7   (B k-row)
    int bc = (t & 31) * 4;          // 0..124

    for (int k0 = 0; k0 < K; k0 += 16) {
        float4 a0 = make_float4(0.f, 0.f, 0.f, 0.f);
        float4 a1 = make_float4(0.f, 0.f, 0.f, 0.f);
        int r0 = bm + ar, r1 = bm + ar + 64;
        if (r0 < M) a0 = *(const float4*)&A[(size_t)r0 * K + k0 + ak];
        if (r1 < M) a1 = *(const float4*)&A[(size_t)r1 * K + k0 + ak];
        float4 b0 = *(const float4*)&B[(size_t)(k0 + br) * Nn + bn + bc];
        float4 b1 = *(const float4*)&B[(size_t)(k0 + br + 8) * Nn + bn + bc];
        __syncthreads();
        As[ak + 0][ar] = a0.x; As[ak + 1][ar] = a0.y;
        As[ak + 2][ar] = a0.z; As[ak + 3][ar] = a0.w;
        As[ak + 0][ar + 64] = a1.x; As[ak + 1][ar + 64] = a1.y;
        As[ak + 2][ar + 64] = a1.z; As[ak + 3][ar + 64] = a1.w;
        *(float4*)&Bs[br][bc]     = b0;
        *(float4*)&Bs[br + 8][bc] = b1;
        __syncthreads();
#pragma unroll
        for (int kk = 0; kk < 16; kk++) {
            float4 al = *(float4*)&As[kk][ty * 4];
            float4 ah = *(float4*)&As[kk][ty * 4 + 64];
            float4 bl = *(float4*)&Bs[kk][tx * 4];
            float4 bh = *(float4*)&Bs[kk][tx * 4 + 64];
            FMA16(acc[0][0], al, bl);
            FMA16(acc[0][1], al, bh);
            FMA16(acc[1][0], ah, bl);
            FMA16(acc[1][1], ah, bh);
        }
    }
    // C write
#pragma unroll
    for (int rh = 0; rh < 2; rh++)
#pragma unroll
    for (int i = 0; i < 4; i++) {
        int row = bm + rh * 64 + ty * 4 + i;
        if (row < M) {
            float4 vlo = make_float4(acc[rh][0][i][0], acc[rh][0][i][1],
                                     acc[rh][0][i][2], acc[rh][0][i][3]);
            float4 vhi = make_float4(acc[rh][1][i][0], acc[rh][1][i][1],
                                     acc[rh][1][i][2], acc[rh][1][i][3]);
            *(float4*)&C[(size_t)row * Nn + bn + tx * 4]      = vlo;
            *(float4*)&C[(size_t)row * Nn + bn + tx * 4 + 64] = vhi;
        }
    }
    // fused attention-score epilogue (2 heads per block)
#pragma unroll
    for (int ch = 0; ch < 2; ch++) {
        int head = blockIdx.y * 2 + ch;
        float4 av = *(const float4*)&a_src[head * 64 + tx * 4];
        float4 dv = *(const float4*)&a_dst[head * 64 + tx * 4];
#pragma unroll
        for (int rh = 0; rh < 2; rh++)
#pragma unroll
        for (int i = 0; i < 4; i++) {
            float ps = acc[rh][ch][i][0] * av.x + acc[rh][ch][i][1] * av.y +
                       acc[rh][ch][i][2] * av.z + acc[rh][ch][i][3] * av.w;
            float pd = acc[rh][ch][i][0] * dv.x + acc[rh][ch][i][1] * dv.y +
                       acc[rh][ch][i][2] * dv.z + acc[rh][ch][i][3] * dv.w;
#pragma unroll
            for (int off = 8; off >= 1; off >>= 1) {
                ps += __shfl_xor(ps, off);
                pd += __shfl_xor(pd, off);
            }
            int row = bm + rh * 64 + ty * 4 + i;
            if (tx == 0 && row < M) {
                s_sc[row * H + head] = ps;
                d_sc[row * H + head] = pd;
            }
        }
    }
}

// ---------------------------------------------------------------- fp32 GEMM 64x64 (layer 3, N=64)
__global__ __launch_bounds__(256) void gemm_kernel(const float* __restrict__ A,
                                                   const float* __restrict__ B,
                                                   float* __restrict__ C,
                                                   int M, int K, int Nn,
                                                   const float* __restrict__ a_src,
                                                   const float* __restrict__ a_dst,
                                                   float* __restrict__ s_sc,
                                                   float* __restrict__ d_sc,
                                                   int H) {
    __shared__ float As[32][65];
    __shared__ float Bs[32][64];
    int t  = threadIdx.x;
    int bm = blockIdx.x * 64;
    int bn = blockIdx.y * 64;
    int tx = t % 16, ty = t / 16;
    float acc[4][4] = {};
    int am0 = t / 8;
    int ak0 = (t % 8) * 4;
    int bk0 = t / 16;
    int bn0 = (t % 16) * 4;

    for (int k0 = 0; k0 < K; k0 += 32) {
        float4 a0 = make_float4(0.f, 0.f, 0.f, 0.f);
        float4 a1 = make_float4(0.f, 0.f, 0.f, 0.f);
        int r0 = bm + am0, r1 = bm + am0 + 32;
        if (r0 < M) a0 = *(const float4*)&A[r0 * K + k0 + ak0];
        if (r1 < M) a1 = *(const float4*)&A[r1 * K + k0 + ak0];
        float4 b0  = *(const float4*)&B[(k0 + bk0) * Nn + bn + bn0];
        float4 b1v = *(const float4*)&B[(k0 + bk0 + 16) * Nn + bn + bn0];
        __syncthreads();
        As[ak0 + 0][am0] = a0.x; As[ak0 + 1][am0] = a0.y;
        As[ak0 + 2][am0] = a0.z; As[ak0 + 3][am0] = a0.w;
        As[ak0 + 0][am0 + 32] = a1.x; As[ak0 + 1][am0 + 32] = a1.y;
        As[ak0 + 2][am0 + 32] = a1.z; As[ak0 + 3][am0 + 32] = a1.w;
        *(float4*)&Bs[bk0][bn0]      = b0;
        *(float4*)&Bs[bk0 + 16][bn0] = b1v;
        __syncthreads();
#pragma unroll
        for (int kk = 0; kk < 32; kk++) {
            float4 av = *(float4*)&As[kk][ty * 4];
            float4 bv = *(float4*)&Bs[kk][tx * 4];
            FMA16(acc, av, bv);
        }
    }
#pragma unroll
    for (int i = 0; i < 4; i++) {
        int row = bm + ty * 4 + i;
        if (row < M) {
            float4 v = make_float4(acc[i][0], acc[i][1], acc[i][2], acc[i][3]);
            *(float4*)&C[row * Nn + bn + tx * 4] = v;
        }
    }
    int head = blockIdx.y;
    float4 av = *(const float4*)&a_src[head * 64 + tx * 4];
    float4 dv = *(const float4*)&a_dst[head * 64 + tx * 4];
#pragma unroll
    for (int i = 0; i < 4; i++) {
        float ps = acc[i][0] * av.x + acc[i][1] * av.y + acc[i][2] * av.z + acc[i][3] * av.w;
        float pd = acc[i][0] * dv.x + acc[i][1] * dv.y + acc[i][2] * dv.z + acc[i][3] * dv.w;
#pragma unroll
        for (int off = 8; off >= 1; off >>= 1) {
            ps += __shfl_xor(ps, off);
            pd += __shfl_xor(pd, off);
        }
        int row = bm + ty * 4 + i;
        if (tx == 0 && row < M) {
            s_sc[row * H + head] = ps;
            d_sc[row * H + head] = pd;
        }
    }
}

// ---------------------------------------------------------------- GAT aggregate
template <int H, int C>
__global__ __launch_bounds__(256) void agg_kernel(const float* __restrict__ hbuf,
                                                  const int* __restrict__ row_ptr,
                                                  const int* __restrict__ csr_src,
                                                  const float* __restrict__ s_sc,
                                                  const float* __restrict__ d_sc,
                                                  const float* __restrict__ bias,
                                                  float* __restrict__ out) {
    constexpr int HC = H * C;
    int w = threadIdx.x >> 6, lane = threadIdx.x & 63;
    int n = blockIdx.x * 4 + w;
    if (n >= NNODES) return;
    int r0 = row_ptr[n], deg = row_ptr[n + 1] - r0;

    float dsc[H];
#pragma unroll
    for (int h = 0; h < H; h++) dsc[h] = d_sc[n * H + h];

    float mx[H];
#pragma unroll
    for (int h = 0; h < H; h++) mx[h] = -INFINITY;
    for (int i = lane; i < deg; i += 64) {
        int s = csr_src[r0 + i];
#pragma unroll
        for (int h = 0; h < H; h++) {
            float e = s_sc[s * H + h] + dsc[h];
            e = (e >= 0.f) ? e : 0.2f * e;
            mx[h] = fmaxf(mx[h], e);
        }
    }
    for (int off = 32; off >= 1; off >>= 1)
#pragma unroll
        for (int h = 0; h < H; h++) mx[h] = fmaxf(mx[h], __shfl_xor(mx[h], off));

    int  myh  = (lane * 4) / C;
    bool fact = (lane * 4) < HC;
    float acc[4] = {0.f, 0.f, 0.f, 0.f};
    float denom = 0.f;
    for (int base = 0; base < deg; base += 64) {
        int cnt = min(64, deg - base);
        int s_local = 0;
        float exl[H];
#pragma unroll
        for (int h = 0; h < H; h++) exl[h] = 0.f;
        if (lane < cnt) {
            s_local = csr_src[r0 + base + lane];
#pragma unroll
            for (int h = 0; h < H; h++) {
                float e = s_sc[s_local * H + h] + dsc[h];
                e = (e >= 0.f) ? e : 0.2f * e;
                exl[h] = expf(e - mx[h]);
            }
        }
        for (int j = 0; j < cnt; j++) {
            int sj = __shfl(s_local, j);
            float exj;
            if constexpr (H == 4) {
                float e0 = __shfl(exl[0], j), e1 = __shfl(exl[1], j);
                float e2 = __shfl(exl[2], j), e3 = __shfl(exl[3], j);
                exj = (myh == 0) ? e0 : (myh == 1) ? e1 : (myh == 2) ? e2 : e3;
            } else {
                exj = __shfl(exl[0], j);
            }
            denom += exj;
            if (fact) {
                float4 hv = *(const float4*)&hbuf[sj * HC + lane * 4];
                acc[0] += exj * hv.x; acc[1] += exj * hv.y;
                acc[2] += exj * hv.z; acc[3] += exj * hv.w;
            }
        }
    }
    if (fact) {
        float inv = 1.0f / (denom + 1e-16f);
#pragma unroll
        for (int k = 0; k < 4; k++) {
            float v = acc[k] * inv + bias[lane * 4 + k];
            v = (v > 0.f) ? v : expm1f(v);   // ELU
            out[n * HC + lane * 4 + k] = v;
        }
    }
}

// ---------------------------------------------------------------- batch pool
__global__ __launch_bounds__(256) void pool_kernel(const float* __restrict__ x,
                                                   const int* __restrict__ batch,
                                                   float* __restrict__ pooled,
                                                   float* __restrict__ cntb) {
    int b = blockIdx.x;
    int lo = 0, hi = NNODES;
    while (lo < hi) { int mid = (lo + hi) >> 1; if (batch[mid] < b) lo = mid + 1; else hi = mid; }
    int start = lo;
    hi = NNODES;
    while (lo < hi) { int mid = (lo + hi) >> 1; if (batch[mid] < b + 1) lo = mid + 1; else hi = mid; }
    int end = lo;

    int t = threadIdx.x;
    int c = t & 63, g = t >> 6;
    float s = 0.f;
    for (int n = start + g; n < end; n += 4) s += x[n * 64 + c];
    __shared__ float buf[4][64];
    buf[g][c] = s;
    __syncthreads();
    if (t < 64) {
        pooled[b * 64 + t] = buf[0][t] + buf[1][t] + buf[2][t] + buf[3][t];
        if (t == 0) cntb[b] = (float)(end - start);
    }
}

// ---------------------------------------------------------------- MLP heads
__global__ __launch_bounds__(256) void head_kernel(const float* __restrict__ pL,
                                                   const float* __restrict__ cL,
                                                   const float* __restrict__ pR,
                                                   const float* __restrict__ cR,
                                                   const float* __restrict__ w1a,
                                                   const float* __restrict__ b1a,
                                                   const float* __restrict__ w2a,
                                                   const float* __restrict__ b2a,
                                                   const float* __restrict__ w1b,
                                                   const float* __restrict__ b1b,
                                                   const float* __restrict__ w2b,
                                                   const float* __restrict__ b2b,
                                                   float* __restrict__ out) {
    int b = blockIdx.x;
    int t = threadIdx.x;
    __shared__ float emb[128];
    __shared__ float ph[4][64];
    __shared__ float h1[64];
    if (t < 64)        emb[t] = pL[b * 64 + t] / fmaxf(cL[b], 1.0f);
    else if (t < 128)  emb[t] = pR[b * 64 + (t - 64)] / fmaxf(cR[b], 1.0f);
    __syncthreads();
    int c = t & 63, g = t >> 6;

    {
        float p = 0.f;
#pragma unroll
        for (int k = 0; k < 32; k++) p += emb[g * 32 + k] * w1a[(g * 32 + k) * 64 + c];
        ph[g][c] = p;
        __syncthreads();
        if (t < 64) h1[t] = fmaxf(ph[0][t] + ph[1][t] + ph[2][t] + ph[3][t] + b1a[t], 0.f);
        __syncthreads();
        if (t < 128) {
            int o = t >> 6, lane = t & 63;
            float q = h1[lane] * w2a[lane * 2 + o];
#pragma unroll
            for (int off = 32; off >= 1; off >>= 1) q += __shfl_xor(q, off);
            if (lane == 0) out[b * 2 + o] = q + b2a[o];
        }
        __syncthreads();
    }
    {
        float p = 0.f;
#pragma unroll
        for (int k = 0; k < 32; k++) p += emb[g * 32 + k] * w1b[(g * 32 + k) * 64 + c];
        ph[g][c] = p;
        __syncthreads();
        if (t < 64) h1[t] = fmaxf(ph[0][t] + ph[1][t] + ph[2][t] + ph[3][t] + b1b[t], 0.f);
        __syncthreads();
        if (t < 128) {
            int o = t >> 6, lane = t & 63;
            float q = h1[lane] * w2b[lane * 2 + o];
#pragma unroll
            for (int off = 32; off >= 1; off >>= 1) q += __shfl_xor(q, off);
            if (lane == 0) out[128 + b * 2 + o] = q + b2b[o];
        }
    }
}

// ---------------------------------------------------------------- launcher
extern "C" void kernel_launch(void* const* d_in, const int* in_sizes, int n_in,
                              void* d_out, int out_size, void* d_ws, size_t ws_size,
                              hipStream_t stream) {
    const float* x_left   = (const float*)d_in[0];
    const float* x_right  = (const float*)d_in[1];
    const int*   ei_left  = (const int*)d_in[2];
    const int*   ei_right = (const int*)d_in[3];
    const int*   ba_left  = (const int*)d_in[4];
    const int*   ba_right = (const int*)d_in[5];
    const float* w1  = (const float*)d_in[6];
    const float* as1 = (const float*)d_in[7];
    const float* ad1 = (const float*)d_in[8];
    const float* b1  = (const float*)d_in[9];
    const float* w2  = (const float*)d_in[10];
    const float* as2 = (const float*)d_in[11];
    const float* ad2 = (const float*)d_in[12];
    const float* b2  = (const float*)d_in[13];
    const float* w3  = (const float*)d_in[14];
    const float* as3 = (const float*)d_in[15];
    const float* ad3 = (const float*)d_in[16];
    const float* b3  = (const float*)d_in[17];
    const float* f1w1 = (const float*)d_in[18];
    const float* f1b1 = (const float*)d_in[19];
    const float* f1w2 = (const float*)d_in[20];
    const float* f1b2 = (const float*)d_in[21];
    const float* f2w1 = (const float*)d_in[22];
    const float* f2b1 = (const float*)d_in[23];
    const float* f2w2 = (const float*)d_in[24];
    const float* f2b2 = (const float*)d_in[25];

    char* w = (char*)d_ws;
    auto carve = [&](size_t bytes) {
        void* p = (void*)w;
        w += (bytes + 255) & ~(size_t)255;
        return p;
    };
    float* buf0    = (float*)carve((size_t)NNODES * 256 * 4);
    float* buf1    = (float*)carve((size_t)NNODES * 256 * 4);
    float* s_sc    = (float*)carve((size_t)NNODES * 4 * 4);
    float* d_sc    = (float*)carve((size_t)NNODES * 4 * 4);
    int*   cnt     = (int*)carve((size_t)NNODES * 4);
    int*   row_ptr = (int*)carve((size_t)(NNODES + 1) * 4);
    int*   fillp   = (int*)carve((size_t)NNODES * 4);
    int*   csr     = (int*)carve((size_t)EPRIME * 4);
    float* pooledL = (float*)carve(64 * 64 * 4);
    float* pooledR = (float*)carve(64 * 64 * 4);
    float* cntbL   = (float*)carve(64 * 4);
    float* cntbR   = (float*)carve(64 * 4);

    const int egrid  = (EPRIME + 255) / 256;
    const int ngrid  = (NNODES + 3) / 4;        // wave-per-node kernels
    const int mgrid  = (NNODES + 63) / 64;      // 64-row gemm tiles
    const int mgrid2 = (NNODES + 127) / 128;    // 128-row gemm tiles

    for (int side = 0; side < 2; side++) {
        const float* x_in  = side ? x_right  : x_left;
        const int*   ei    = side ? ei_right : ei_left;
        const int*   batch = side ? ba_right : ba_left;
        float* pooled = side ? pooledR : pooledL;
        float* cntb   = side ? cntbR   : cntbL;

        // CSR by dst (shared across the 3 layers)
        hipMemsetAsync(cnt, 0, (size_t)NNODES * 4, stream);
        count_kernel<<<egrid, 256, 0, stream>>>(ei, cnt);
        scan_kernel<<<1, 1024, 0, stream>>>(cnt, row_ptr, fillp);
        fill_kernel<<<egrid, 256, 0, stream>>>(ei, fillp, csr);

        // layer 1: x[N,128] @ w1[128,256] + fused scores
        gemm128_kernel<<<dim3(mgrid2, 2), 256, 0, stream>>>(x_in, w1, buf0, NNODES, 128,
                                                            as1, ad1, s_sc, d_sc);
        agg_kernel<4, 64><<<ngrid, 256, 0, stream>>>(buf0, row_ptr, csr, s_sc, d_sc, b1, buf1);

        // layer 2: buf1[N,256] @ w2[256,256] + fused scores
        gemm128_kernel<<<dim3(mgrid2, 2), 256, 0, stream>>>(buf1, w2, buf0, NNODES, 256,
                                                            as2, ad2, s_sc, d_sc);
        agg_kernel<4, 64><<<ngrid, 256, 0, stream>>>(buf0, row_ptr, csr, s_sc, d_sc, b2, buf1);

        // layer 3: buf1[N,256] @ w3[256,64], single head + fused scores
        gemm_kernel<<<dim3(mgrid, 1), 256, 0, stream>>>(buf1, w3, buf0, NNODES, 256, 64,
                                                        as3, ad3, s_sc, d_sc, 1);
        agg_kernel<1, 64><<<ngrid, 256, 0, stream>>>(buf0, row_ptr, csr, s_sc, d_sc, b3, buf1);

        // batch mean-pool
        pool_kernel<<<NBATCH, 256, 0, stream>>>(buf1, batch, pooled, cntb);
    }

    head_kernel<<<NBATCH, 256, 0, stream>>>(pooledL, cntbL, pooledR, cntbR,
                                            f1w1, f1b1, f1w2, f1b2,
                                            f2w1, f2b1, f2w2, f2b2,
                                            (float*)d_out);
}

// Round 6
// 759.423 us; speedup vs baseline: 1.1191x; 1.1191x over previous
//
#include <hip/hip_runtime.h>
#include <cstdint>
#include <cstddef>

#define NNODES 20000
#define NEDGES 320000
#define NBATCH 64
#define EPRIME (NEDGES + NNODES)

// ---------------------------------------------------------------- CSR build
__global__ __launch_bounds__(256) void count_kernel(const int* __restrict__ ei,
                                                    int* __restrict__ cnt) {
    int k = blockIdx.x * 256 + threadIdx.x;
    if (k >= EPRIME) return;
    int dst = (k < NEDGES) ? ei[NEDGES + k] : (k - NEDGES);
    atomicAdd(&cnt[dst], 1);
}

// Register-blocked exclusive scan: 1 block x 1024 threads x 20 elems/thread.
__global__ __launch_bounds__(1024) void scan_kernel(const int* __restrict__ cnt,
                                                    int* __restrict__ row_ptr,
                                                    int* __restrict__ fillp) {
    constexpr int CHUNK = 20;              // 1024*20 = 20480 >= NNODES
    int t = threadIdx.x;
    int base = t * CHUNK;
    int v[CHUNK];
    int sum = 0;
#pragma unroll
    for (int i = 0; i < CHUNK; i++) {
        int idx = base + i;
        v[i] = (idx < NNODES) ? cnt[idx] : 0;
        sum += v[i];
    }
    int lane = t & 63, wid = t >> 6;       // 16 waves
    int s = sum;
    for (int off = 1; off < 64; off <<= 1) {
        int x = __shfl_up(s, off);
        if (lane >= off) s += x;
    }
    __shared__ int wsum[16];
    __shared__ int woff[17];
    if (lane == 63) wsum[wid] = s;
    __syncthreads();
    if (t == 0) {
        int acc = 0;
        for (int i = 0; i < 16; i++) { woff[i] = acc; acc += wsum[i]; }
        woff[16] = acc;
    }
    __syncthreads();
    int excl = woff[wid] + s - sum;        // exclusive prefix at chunk start
#pragma unroll
    for (int i = 0; i < CHUNK; i++) {
        int idx = base + i;
        if (idx < NNODES) { row_ptr[idx] = excl; fillp[idx] = excl; }
        excl += v[i];
    }
    if (t == 0) row_ptr[NNODES] = woff[16];
}

__global__ __launch_bounds__(256) void fill_kernel(const int* __restrict__ ei,
                                                   int* __restrict__ fillp,
                                                   int* __restrict__ csr_src) {
    int k = blockIdx.x * 256 + threadIdx.x;
    if (k >= EPRIME) return;
    int src, dst;
    if (k < NEDGES) { src = ei[k]; dst = ei[NEDGES + k]; }
    else            { src = k - NEDGES; dst = src; }
    int pos = atomicAdd(&fillp[dst], 1);
    csr_src[pos] = src;
}

#define FMA16(ACC, AV, BV)                                        \
    ACC[0][0] += AV.x * BV.x; ACC[0][1] += AV.x * BV.y;           \
    ACC[0][2] += AV.x * BV.z; ACC[0][3] += AV.x * BV.w;           \
    ACC[1][0] += AV.y * BV.x; ACC[1][1] += AV.y * BV.y;           \
    ACC[1][2] += AV.y * BV.z; ACC[1][3] += AV.y * BV.w;           \
    ACC[2][0] += AV.z * BV.x; ACC[2][1] += AV.z * BV.y;           \
    ACC[2][2] += AV.z * BV.z; ACC[2][3] += AV.z * BV.w;           \
    ACC[3][0] += AV.w * BV.x; ACC[3][1] += AV.w * BV.y;           \
    ACC[3][2] += AV.w * BV.z; ACC[3][3] += AV.w * BV.w;

// ---------------------------------------------------------------- fp32 GEMM 128x64
// C[M,Nn] = A[M,K] @ B[K,Nn]. BM=128, BN=64, BK=16, 256 threads, 8x4/thread.
// Per kk: 32 FMA (64 VALU cyc) vs 3 ds_read_b128 (~36 LDS cyc) -> VALU-dominant.
// Grid (ceil(M/128), Nn/64) keeps >600 blocks. N-tile = 64 = one head ->
// fused score epilogue with head = blockIdx.y.
// As scalar-store banking: groups (t&1) cover all 32 banks exactly 2x (free).
__global__ __launch_bounds__(256) void gemm128x64_kernel(const float* __restrict__ A,
                                                         const float* __restrict__ B,
                                                         float* __restrict__ C,
                                                         int M, int K, int Nn,
                                                         const float* __restrict__ a_src,
                                                         const float* __restrict__ a_dst,
                                                         float* __restrict__ s_sc,
                                                         float* __restrict__ d_sc,
                                                         int H) {
    __shared__ float As[16][129];   // transposed, +1 pad
    __shared__ float Bs[16][64];
    int t  = threadIdx.x;
    int bm = blockIdx.x * 128;
    int bn = blockIdx.y * 64;
    int tx = t & 15, ty = t >> 4;   // 16x16 thread grid; 8 rows x 4 cols each
    float acc[2][4][4] = {};        // [rowhalf(4)][i][j]

    int ar  = t >> 1;               // 0..127 (A row within tile)
    int akc = (t & 1) * 8;          // 0 or 8 (k-chunk)
    int br  = t >> 4;               // 0..15  (B k-row)
    int bc  = (t & 15) * 4;         // 0..60

    for (int k0 = 0; k0 < K; k0 += 16) {
        float4 a0 = make_float4(0.f, 0.f, 0.f, 0.f);
        float4 a1 = make_float4(0.f, 0.f, 0.f, 0.f);
        int r = bm + ar;
        if (r < M) {
            a0 = *(const float4*)&A[(size_t)r * K + k0 + akc];
            a1 = *(const float4*)&A[(size_t)r * K + k0 + akc + 4];
        }
        float4 b0 = *(const float4*)&B[(size_t)(k0 + br) * Nn + bn + bc];
        __syncthreads();
        As[akc + 0][ar] = a0.x; As[akc + 1][ar] = a0.y;
        As[akc + 2][ar] = a0.z; As[akc + 3][ar] = a0.w;
        As[akc + 4][ar] = a1.x; As[akc + 5][ar] = a1.y;
        As[akc + 6][ar] = a1.z; As[akc + 7][ar] = a1.w;
        *(float4*)&Bs[br][bc] = b0;
        __syncthreads();
#pragma unroll
        for (int kk = 0; kk < 16; kk++) {
            float4 al = *(float4*)&As[kk][ty * 8];
            float4 ah = *(float4*)&As[kk][ty * 8 + 4];
            float4 bv = *(float4*)&Bs[kk][tx * 4];
            FMA16(acc[0], al, bv);
            FMA16(acc[1], ah, bv);
        }
    }
    // C write
#pragma unroll
    for (int h = 0; h < 2; h++)
#pragma unroll
    for (int i = 0; i < 4; i++) {
        int row = bm + ty * 8 + h * 4 + i;
        if (row < M) {
            float4 v = make_float4(acc[h][i][0], acc[h][i][1], acc[h][i][2], acc[h][i][3]);
            *(float4*)&C[(size_t)row * Nn + bn + tx * 4] = v;
        }
    }
    // fused attention-score epilogue (one head per block column)
    int head = blockIdx.y;
    float4 av = *(const float4*)&a_src[head * 64 + tx * 4];
    float4 dv = *(const float4*)&a_dst[head * 64 + tx * 4];
#pragma unroll
    for (int h = 0; h < 2; h++)
#pragma unroll
    for (int i = 0; i < 4; i++) {
        float ps = acc[h][i][0] * av.x + acc[h][i][1] * av.y +
                   acc[h][i][2] * av.z + acc[h][i][3] * av.w;
        float pd = acc[h][i][0] * dv.x + acc[h][i][1] * dv.y +
                   acc[h][i][2] * dv.z + acc[h][i][3] * dv.w;
#pragma unroll
        for (int off = 8; off >= 1; off >>= 1) {
            ps += __shfl_xor(ps, off);
            pd += __shfl_xor(pd, off);
        }
        int row = bm + ty * 8 + h * 4 + i;
        if (tx == 0 && row < M) {
            s_sc[row * H + head] = ps;
            d_sc[row * H + head] = pd;
        }
    }
}

// ---------------------------------------------------------------- fp32 GEMM 64x64 (layer 3, N=64)
__global__ __launch_bounds__(256) void gemm_kernel(const float* __restrict__ A,
                                                   const float* __restrict__ B,
                                                   float* __restrict__ C,
                                                   int M, int K, int Nn,
                                                   const float* __restrict__ a_src,
                                                   const float* __restrict__ a_dst,
                                                   float* __restrict__ s_sc,
                                                   float* __restrict__ d_sc,
                                                   int H) {
    __shared__ float As[32][65];
    __shared__ float Bs[32][64];
    int t  = threadIdx.x;
    int bm = blockIdx.x * 64;
    int bn = blockIdx.y * 64;
    int tx = t % 16, ty = t / 16;
    float acc[4][4] = {};
    int am0 = t / 8;
    int ak0 = (t % 8) * 4;
    int bk0 = t / 16;
    int bn0 = (t % 16) * 4;

    for (int k0 = 0; k0 < K; k0 += 32) {
        float4 a0 = make_float4(0.f, 0.f, 0.f, 0.f);
        float4 a1 = make_float4(0.f, 0.f, 0.f, 0.f);
        int r0 = bm + am0, r1 = bm + am0 + 32;
        if (r0 < M) a0 = *(const float4*)&A[r0 * K + k0 + ak0];
        if (r1 < M) a1 = *(const float4*)&A[r1 * K + k0 + ak0];
        float4 b0  = *(const float4*)&B[(k0 + bk0) * Nn + bn + bn0];
        float4 b1v = *(const float4*)&B[(k0 + bk0 + 16) * Nn + bn + bn0];
        __syncthreads();
        As[ak0 + 0][am0] = a0.x; As[ak0 + 1][am0] = a0.y;
        As[ak0 + 2][am0] = a0.z; As[ak0 + 3][am0] = a0.w;
        As[ak0 + 0][am0 + 32] = a1.x; As[ak0 + 1][am0 + 32] = a1.y;
        As[ak0 + 2][am0 + 32] = a1.z; As[ak0 + 3][am0 + 32] = a1.w;
        *(float4*)&Bs[bk0][bn0]      = b0;
        *(float4*)&Bs[bk0 + 16][bn0] = b1v;
        __syncthreads();
#pragma unroll
        for (int kk = 0; kk < 32; kk++) {
            float4 av = *(float4*)&As[kk][ty * 4];
            float4 bv = *(float4*)&Bs[kk][tx * 4];
            FMA16(acc, av, bv);
        }
    }
#pragma unroll
    for (int i = 0; i < 4; i++) {
        int row = bm + ty * 4 + i;
        if (row < M) {
            float4 v = make_float4(acc[i][0], acc[i][1], acc[i][2], acc[i][3]);
            *(float4*)&C[row * Nn + bn + tx * 4] = v;
        }
    }
    int head = blockIdx.y;
    float4 av = *(const float4*)&a_src[head * 64 + tx * 4];
    float4 dv = *(const float4*)&a_dst[head * 64 + tx * 4];
#pragma unroll
    for (int i = 0; i < 4; i++) {
        float ps = acc[i][0] * av.x + acc[i][1] * av.y + acc[i][2] * av.z + acc[i][3] * av.w;
        float pd = acc[i][0] * dv.x + acc[i][1] * dv.y + acc[i][2] * dv.z + acc[i][3] * dv.w;
#pragma unroll
        for (int off = 8; off >= 1; off >>= 1) {
            ps += __shfl_xor(ps, off);
            pd += __shfl_xor(pd, off);
        }
        int row = bm + ty * 4 + i;
        if (tx == 0 && row < M) {
            s_sc[row * H + head] = ps;
            d_sc[row * H + head] = pd;
        }
    }
}

// ---------------------------------------------------------------- GAT aggregate
template <int H, int C>
__global__ __launch_bounds__(256) void agg_kernel(const float* __restrict__ hbuf,
                                                  const int* __restrict__ row_ptr,
                                                  const int* __restrict__ csr_src,
                                                  const float* __restrict__ s_sc,
                                                  const float* __restrict__ d_sc,
                                                  const float* __restrict__ bias,
                                                  float* __restrict__ out) {
    constexpr int HC = H * C;
    int w = threadIdx.x >> 6, lane = threadIdx.x & 63;
    int n = blockIdx.x * 4 + w;
    if (n >= NNODES) return;
    int r0 = row_ptr[n], deg = row_ptr[n + 1] - r0;

    float dsc[H];
#pragma unroll
    for (int h = 0; h < H; h++) dsc[h] = d_sc[n * H + h];

    float mx[H];
#pragma unroll
    for (int h = 0; h < H; h++) mx[h] = -INFINITY;
    for (int i = lane; i < deg; i += 64) {
        int s = csr_src[r0 + i];
#pragma unroll
        for (int h = 0; h < H; h++) {
            float e = s_sc[s * H + h] + dsc[h];
            e = (e >= 0.f) ? e : 0.2f * e;
            mx[h] = fmaxf(mx[h], e);
        }
    }
    for (int off = 32; off >= 1; off >>= 1)
#pragma unroll
        for (int h = 0; h < H; h++) mx[h] = fmaxf(mx[h], __shfl_xor(mx[h], off));

    int  myh  = (lane * 4) / C;
    bool fact = (lane * 4) < HC;
    float acc[4] = {0.f, 0.f, 0.f, 0.f};
    float denom = 0.f;
    for (int base = 0; base < deg; base += 64) {
        int cnt = min(64, deg - base);
        int s_local = 0;
        float exl[H];
#pragma unroll
        for (int h = 0; h < H; h++) exl[h] = 0.f;
        if (lane < cnt) {
            s_local = csr_src[r0 + base + lane];
#pragma unroll
            for (int h = 0; h < H; h++) {
                float e = s_sc[s_local * H + h] + dsc[h];
                e = (e >= 0.f) ? e : 0.2f * e;
                exl[h] = expf(e - mx[h]);
            }
        }
        for (int j = 0; j < cnt; j++) {
            int sj = __shfl(s_local, j);
            float exj;
            if constexpr (H == 4) {
                float e0 = __shfl(exl[0], j), e1 = __shfl(exl[1], j);
                float e2 = __shfl(exl[2], j), e3 = __shfl(exl[3], j);
                exj = (myh == 0) ? e0 : (myh == 1) ? e1 : (myh == 2) ? e2 : e3;
            } else {
                exj = __shfl(exl[0], j);
            }
            denom += exj;
            if (fact) {
                float4 hv = *(const float4*)&hbuf[sj * HC + lane * 4];
                acc[0] += exj * hv.x; acc[1] += exj * hv.y;
                acc[2] += exj * hv.z; acc[3] += exj * hv.w;
            }
        }
    }
    if (fact) {
        float inv = 1.0f / (denom + 1e-16f);
#pragma unroll
        for (int k = 0; k < 4; k++) {
            float v = acc[k] * inv + bias[lane * 4 + k];
            v = (v > 0.f) ? v : expm1f(v);   // ELU
            out[n * HC + lane * 4 + k] = v;
        }
    }
}

// ---------------------------------------------------------------- batch pool
__global__ __launch_bounds__(256) void pool_kernel(const float* __restrict__ x,
                                                   const int* __restrict__ batch,
                                                   float* __restrict__ pooled,
                                                   float* __restrict__ cntb) {
    int b = blockIdx.x;
    int lo = 0, hi = NNODES;
    while (lo < hi) { int mid = (lo + hi) >> 1; if (batch[mid] < b) lo = mid + 1; else hi = mid; }
    int start = lo;
    hi = NNODES;
    while (lo < hi) { int mid = (lo + hi) >> 1; if (batch[mid] < b + 1) lo = mid + 1; else hi = mid; }
    int end = lo;

    int t = threadIdx.x;
    int c = t & 63, g = t >> 6;
    float s = 0.f;
    for (int n = start + g; n < end; n += 4) s += x[n * 64 + c];
    __shared__ float buf[4][64];
    buf[g][c] = s;
    __syncthreads();
    if (t < 64) {
        pooled[b * 64 + t] = buf[0][t] + buf[1][t] + buf[2][t] + buf[3][t];
        if (t == 0) cntb[b] = (float)(end - start);
    }
}

// ---------------------------------------------------------------- MLP heads
__global__ __launch_bounds__(256) void head_kernel(const float* __restrict__ pL,
                                                   const float* __restrict__ cL,
                                                   const float* __restrict__ pR,
                                                   const float* __restrict__ cR,
                                                   const float* __restrict__ w1a,
                                                   const float* __restrict__ b1a,
                                                   const float* __restrict__ w2a,
                                                   const float* __restrict__ b2a,
                                                   const float* __restrict__ w1b,
                                                   const float* __restrict__ b1b,
                                                   const float* __restrict__ w2b,
                                                   const float* __restrict__ b2b,
                                                   float* __restrict__ out) {
    int b = blockIdx.x;
    int t = threadIdx.x;
    __shared__ float emb[128];
    __shared__ float ph[4][64];
    __shared__ float h1[64];
    if (t < 64)        emb[t] = pL[b * 64 + t] / fmaxf(cL[b], 1.0f);
    else if (t < 128)  emb[t] = pR[b * 64 + (t - 64)] / fmaxf(cR[b], 1.0f);
    __syncthreads();
    int c = t & 63, g = t >> 6;

    {
        float p = 0.f;
#pragma unroll
        for (int k = 0; k < 32; k++) p += emb[g * 32 + k] * w1a[(g * 32 + k) * 64 + c];
        ph[g][c] = p;
        __syncthreads();
        if (t < 64) h1[t] = fmaxf(ph[0][t] + ph[1][t] + ph[2][t] + ph[3][t] + b1a[t], 0.f);
        __syncthreads();
        if (t < 128) {
            int o = t >> 6, lane = t & 63;
            float q = h1[lane] * w2a[lane * 2 + o];
#pragma unroll
            for (int off = 32; off >= 1; off >>= 1) q += __shfl_xor(q, off);
            if (lane == 0) out[b * 2 + o] = q + b2a[o];
        }
        __syncthreads();
    }
    {
        float p = 0.f;
#pragma unroll
        for (int k = 0; k < 32; k++) p += emb[g * 32 + k] * w1b[(g * 32 + k) * 64 + c];
        ph[g][c] = p;
        __syncthreads();
        if (t < 64) h1[t] = fmaxf(ph[0][t] + ph[1][t] + ph[2][t] + ph[3][t] + b1b[t], 0.f);
        __syncthreads();
        if (t < 128) {
            int o = t >> 6, lane = t & 63;
            float q = h1[lane] * w2b[lane * 2 + o];
#pragma unroll
            for (int off = 32; off >= 1; off >>= 1) q += __shfl_xor(q, off);
            if (lane == 0) out[128 + b * 2 + o] = q + b2b[o];
        }
    }
}

// ---------------------------------------------------------------- launcher
extern "C" void kernel_launch(void* const* d_in, const int* in_sizes, int n_in,
                              void* d_out, int out_size, void* d_ws, size_t ws_size,
                              hipStream_t stream) {
    const float* x_left   = (const float*)d_in[0];
    const float* x_right  = (const float*)d_in[1];
    const int*   ei_left  = (const int*)d_in[2];
    const int*   ei_right = (const int*)d_in[3];
    const int*   ba_left  = (const int*)d_in[4];
    const int*   ba_right = (const int*)d_in[5];
    const float* w1  = (const float*)d_in[6];
    const float* as1 = (const float*)d_in[7];
    const float* ad1 = (const float*)d_in[8];
    const float* b1  = (const float*)d_in[9];
    const float* w2  = (const float*)d_in[10];
    const float* as2 = (const float*)d_in[11];
    const float* ad2 = (const float*)d_in[12];
    const float* b2  = (const float*)d_in[13];
    const float* w3  = (const float*)d_in[14];
    const float* as3 = (const float*)d_in[15];
    const float* ad3 = (const float*)d_in[16];
    const float* b3  = (const float*)d_in[17];
    const float* f1w1 = (const float*)d_in[18];
    const float* f1b1 = (const float*)d_in[19];
    const float* f1w2 = (const float*)d_in[20];
    const float* f1b2 = (const float*)d_in[21];
    const float* f2w1 = (const float*)d_in[22];
    const float* f2b1 = (const float*)d_in[23];
    const float* f2w2 = (const float*)d_in[24];
    const float* f2b2 = (const float*)d_in[25];

    char* w = (char*)d_ws;
    auto carve = [&](size_t bytes) {
        void* p = (void*)w;
        w += (bytes + 255) & ~(size_t)255;
        return p;
    };
    float* buf0    = (float*)carve((size_t)NNODES * 256 * 4);
    float* buf1    = (float*)carve((size_t)NNODES * 256 * 4);
    float* s_sc    = (float*)carve((size_t)NNODES * 4 * 4);
    float* d_sc    = (float*)carve((size_t)NNODES * 4 * 4);
    int*   cnt     = (int*)carve((size_t)NNODES * 4);
    int*   row_ptr = (int*)carve((size_t)(NNODES + 1) * 4);
    int*   fillp   = (int*)carve((size_t)NNODES * 4);
    int*   csr     = (int*)carve((size_t)EPRIME * 4);
    float* pooledL = (float*)carve(64 * 64 * 4);
    float* pooledR = (float*)carve(64 * 64 * 4);
    float* cntbL   = (float*)carve(64 * 4);
    float* cntbR   = (float*)carve(64 * 4);

    const int egrid  = (EPRIME + 255) / 256;
    const int ngrid  = (NNODES + 3) / 4;        // wave-per-node kernels
    const int mgrid  = (NNODES + 63) / 64;      // 64-row gemm tiles
    const int mgrid2 = (NNODES + 127) / 128;    // 128-row gemm tiles

    for (int side = 0; side < 2; side++) {
        const float* x_in  = side ? x_right  : x_left;
        const int*   ei    = side ? ei_right : ei_left;
        const int*   batch = side ? ba_right : ba_left;
        float* pooled = side ? pooledR : pooledL;
        float* cntb   = side ? cntbR   : cntbL;

        // CSR by dst (shared across the 3 layers)
        hipMemsetAsync(cnt, 0, (size_t)NNODES * 4, stream);
        count_kernel<<<egrid, 256, 0, stream>>>(ei, cnt);
        scan_kernel<<<1, 1024, 0, stream>>>(cnt, row_ptr, fillp);
        fill_kernel<<<egrid, 256, 0, stream>>>(ei, fillp, csr);

        // layer 1: x[N,128] @ w1[128,256] + fused scores
        gemm128x64_kernel<<<dim3(mgrid2, 4), 256, 0, stream>>>(x_in, w1, buf0, NNODES, 128, 256,
                                                               as1, ad1, s_sc, d_sc, 4);
        agg_kernel<4, 64><<<ngrid, 256, 0, stream>>>(buf0, row_ptr, csr, s_sc, d_sc, b1, buf1);

        // layer 2: buf1[N,256] @ w2[256,256] + fused scores
        gemm128x64_kernel<<<dim3(mgrid2, 4), 256, 0, stream>>>(buf1, w2, buf0, NNODES, 256, 256,
                                                               as2, ad2, s_sc, d_sc, 4);
        agg_kernel<4, 64><<<ngrid, 256, 0, stream>>>(buf0, row_ptr, csr, s_sc, d_sc, b2, buf1);

        // layer 3: buf1[N,256] @ w3[256,64], single head + fused scores
        gemm_kernel<<<dim3(mgrid, 1), 256, 0, stream>>>(buf1, w3, buf0, NNODES, 256, 64,
                                                        as3, ad3, s_sc, d_sc, 1);
        agg_kernel<1, 64><<<ngrid, 256, 0, stream>>>(buf0, row_ptr, csr, s_sc, d_sc, b3, buf1);

        // batch mean-pool
        pool_kernel<<<NBATCH, 256, 0, stream>>>(buf1, batch, pooled, cntb);
    }

    head_kernel<<<NBATCH, 256, 0, stream>>>(pooledL, cntbL, pooledR, cntbR,
                                            f1w1, f1b1, f1w2, f1b2,
                                            f2w1, f2b1, f2w2, f2b2,
                                            (float*)d_out);
}

// Round 7
// 721.877 us; speedup vs baseline: 1.1773x; 1.0520x over previous
//
#include <hip/hip_runtime.h>
#include <cstdint>
#include <cstddef>

#define NNODES 20000
#define NEDGES 320000
#define NBATCH 64
#define EPRIME (NEDGES + NNODES)

// ---------------------------------------------------------------- CSR build
__global__ __launch_bounds__(256) void count_kernel(const int* __restrict__ ei,
                                                    int* __restrict__ cnt) {
    int k = blockIdx.x * 256 + threadIdx.x;
    if (k >= EPRIME) return;
    int dst = (k < NEDGES) ? ei[NEDGES + k] : (k - NEDGES);
    atomicAdd(&cnt[dst], 1);
}

// Register-blocked exclusive scan: 1 block x 1024 threads x 20 elems/thread.
__global__ __launch_bounds__(1024) void scan_kernel(const int* __restrict__ cnt,
                                                    int* __restrict__ row_ptr,
                                                    int* __restrict__ fillp) {
    constexpr int CHUNK = 20;              // 1024*20 = 20480 >= NNODES
    int t = threadIdx.x;
    int base = t * CHUNK;
    int v[CHUNK];
    int sum = 0;
#pragma unroll
    for (int i = 0; i < CHUNK; i++) {
        int idx = base + i;
        v[i] = (idx < NNODES) ? cnt[idx] : 0;
        sum += v[i];
    }
    int lane = t & 63, wid = t >> 6;       // 16 waves
    int s = sum;
    for (int off = 1; off < 64; off <<= 1) {
        int x = __shfl_up(s, off);
        if (lane >= off) s += x;
    }
    __shared__ int wsum[16];
    __shared__ int woff[17];
    if (lane == 63) wsum[wid] = s;
    __syncthreads();
    if (t == 0) {
        int acc = 0;
        for (int i = 0; i < 16; i++) { woff[i] = acc; acc += wsum[i]; }
        woff[16] = acc;
    }
    __syncthreads();
    int excl = woff[wid] + s - sum;        // exclusive prefix at chunk start
#pragma unroll
    for (int i = 0; i < CHUNK; i++) {
        int idx = base + i;
        if (idx < NNODES) { row_ptr[idx] = excl; fillp[idx] = excl; }
        excl += v[i];
    }
    if (t == 0) row_ptr[NNODES] = woff[16];
}

__global__ __launch_bounds__(256) void fill_kernel(const int* __restrict__ ei,
                                                   int* __restrict__ fillp,
                                                   int* __restrict__ csr_src) {
    int k = blockIdx.x * 256 + threadIdx.x;
    if (k >= EPRIME) return;
    int src, dst;
    if (k < NEDGES) { src = ei[k]; dst = ei[NEDGES + k]; }
    else            { src = k - NEDGES; dst = src; }
    int pos = atomicAdd(&fillp[dst], 1);
    csr_src[pos] = src;
}

#define FMA16(ACC, AV, BV)                                        \
    ACC[0][0] += AV.x * BV.x; ACC[0][1] += AV.x * BV.y;           \
    ACC[0][2] += AV.x * BV.z; ACC[0][3] += AV.x * BV.w;           \
    ACC[1][0] += AV.y * BV.x; ACC[1][1] += AV.y * BV.y;           \
    ACC[1][2] += AV.y * BV.z; ACC[1][3] += AV.y * BV.w;           \
    ACC[2][0] += AV.z * BV.x; ACC[2][1] += AV.z * BV.y;           \
    ACC[2][2] += AV.z * BV.z; ACC[2][3] += AV.z * BV.w;           \
    ACC[3][0] += AV.w * BV.x; ACC[3][1] += AV.w * BV.y;           \
    ACC[3][2] += AV.w * BV.z; ACC[3][3] += AV.w * BV.w;

// ---------------------------------------------------------------- fp32 GEMM 128x64
// BM=128, BN=64, BK=16, 256 threads, 8x4/thread. Fused score epilogue.
__global__ __launch_bounds__(256) void gemm128x64_kernel(const float* __restrict__ A,
                                                         const float* __restrict__ B,
                                                         float* __restrict__ C,
                                                         int M, int K, int Nn,
                                                         const float* __restrict__ a_src,
                                                         const float* __restrict__ a_dst,
                                                         float* __restrict__ s_sc,
                                                         float* __restrict__ d_sc,
                                                         int H) {
    __shared__ float As[16][129];   // transposed, +1 pad
    __shared__ float Bs[16][64];
    int t  = threadIdx.x;
    int bm = blockIdx.x * 128;
    int bn = blockIdx.y * 64;
    int tx = t & 15, ty = t >> 4;   // 16x16 thread grid; 8 rows x 4 cols each
    float acc[2][4][4] = {};

    int ar  = t >> 1;               // 0..127 (A row within tile)
    int akc = (t & 1) * 8;          // 0 or 8 (k-chunk)
    int br  = t >> 4;               // 0..15  (B k-row)
    int bc  = (t & 15) * 4;         // 0..60

    for (int k0 = 0; k0 < K; k0 += 16) {
        float4 a0 = make_float4(0.f, 0.f, 0.f, 0.f);
        float4 a1 = make_float4(0.f, 0.f, 0.f, 0.f);
        int r = bm + ar;
        if (r < M) {
            a0 = *(const float4*)&A[(size_t)r * K + k0 + akc];
            a1 = *(const float4*)&A[(size_t)r * K + k0 + akc + 4];
        }
        float4 b0 = *(const float4*)&B[(size_t)(k0 + br) * Nn + bn + bc];
        __syncthreads();
        As[akc + 0][ar] = a0.x; As[akc + 1][ar] = a0.y;
        As[akc + 2][ar] = a0.z; As[akc + 3][ar] = a0.w;
        As[akc + 4][ar] = a1.x; As[akc + 5][ar] = a1.y;
        As[akc + 6][ar] = a1.z; As[akc + 7][ar] = a1.w;
        *(float4*)&Bs[br][bc] = b0;
        __syncthreads();
#pragma unroll
        for (int kk = 0; kk < 16; kk++) {
            float4 al = *(float4*)&As[kk][ty * 8];
            float4 ah = *(float4*)&As[kk][ty * 8 + 4];
            float4 bv = *(float4*)&Bs[kk][tx * 4];
            FMA16(acc[0], al, bv);
            FMA16(acc[1], ah, bv);
        }
    }
#pragma unroll
    for (int h = 0; h < 2; h++)
#pragma unroll
    for (int i = 0; i < 4; i++) {
        int row = bm + ty * 8 + h * 4 + i;
        if (row < M) {
            float4 v = make_float4(acc[h][i][0], acc[h][i][1], acc[h][i][2], acc[h][i][3]);
            *(float4*)&C[(size_t)row * Nn + bn + tx * 4] = v;
        }
    }
    int head = blockIdx.y;
    float4 av = *(const float4*)&a_src[head * 64 + tx * 4];
    float4 dv = *(const float4*)&a_dst[head * 64 + tx * 4];
#pragma unroll
    for (int h = 0; h < 2; h++)
#pragma unroll
    for (int i = 0; i < 4; i++) {
        float ps = acc[h][i][0] * av.x + acc[h][i][1] * av.y +
                   acc[h][i][2] * av.z + acc[h][i][3] * av.w;
        float pd = acc[h][i][0] * dv.x + acc[h][i][1] * dv.y +
                   acc[h][i][2] * dv.z + acc[h][i][3] * dv.w;
#pragma unroll
        for (int off = 8; off >= 1; off >>= 1) {
            ps += __shfl_xor(ps, off);
            pd += __shfl_xor(pd, off);
        }
        int row = bm + ty * 8 + h * 4 + i;
        if (tx == 0 && row < M) {
            s_sc[row * H + head] = ps;
            d_sc[row * H + head] = pd;
        }
    }
}

// ---------------------------------------------------------------- fp32 GEMM 64x64 (layer 3, N=64)
__global__ __launch_bounds__(256) void gemm_kernel(const float* __restrict__ A,
                                                   const float* __restrict__ B,
                                                   float* __restrict__ C,
                                                   int M, int K, int Nn,
                                                   const float* __restrict__ a_src,
                                                   const float* __restrict__ a_dst,
                                                   float* __restrict__ s_sc,
                                                   float* __restrict__ d_sc,
                                                   int H) {
    __shared__ float As[32][65];
    __shared__ float Bs[32][64];
    int t  = threadIdx.x;
    int bm = blockIdx.x * 64;
    int bn = blockIdx.y * 64;
    int tx = t % 16, ty = t / 16;
    float acc[4][4] = {};
    int am0 = t / 8;
    int ak0 = (t % 8) * 4;
    int bk0 = t / 16;
    int bn0 = (t % 16) * 4;

    for (int k0 = 0; k0 < K; k0 += 32) {
        float4 a0 = make_float4(0.f, 0.f, 0.f, 0.f);
        float4 a1 = make_float4(0.f, 0.f, 0.f, 0.f);
        int r0 = bm + am0, r1 = bm + am0 + 32;
        if (r0 < M) a0 = *(const float4*)&A[r0 * K + k0 + ak0];
        if (r1 < M) a1 = *(const float4*)&A[r1 * K + k0 + ak0];
        float4 b0  = *(const float4*)&B[(k0 + bk0) * Nn + bn + bn0];
        float4 b1v = *(const float4*)&B[(k0 + bk0 + 16) * Nn + bn + bn0];
        __syncthreads();
        As[ak0 + 0][am0] = a0.x; As[ak0 + 1][am0] = a0.y;
        As[ak0 + 2][am0] = a0.z; As[ak0 + 3][am0] = a0.w;
        As[ak0 + 0][am0 + 32] = a1.x; As[ak0 + 1][am0 + 32] = a1.y;
        As[ak0 + 2][am0 + 32] = a1.z; As[ak0 + 3][am0 + 32] = a1.w;
        *(float4*)&Bs[bk0][bn0]      = b0;
        *(float4*)&Bs[bk0 + 16][bn0] = b1v;
        __syncthreads();
#pragma unroll
        for (int kk = 0; kk < 32; kk++) {
            float4 av = *(float4*)&As[kk][ty * 4];
            float4 bv = *(float4*)&Bs[kk][tx * 4];
            FMA16(acc, av, bv);
        }
    }
#pragma unroll
    for (int i = 0; i < 4; i++) {
        int row = bm + ty * 4 + i;
        if (row < M) {
            float4 v = make_float4(acc[i][0], acc[i][1], acc[i][2], acc[i][3]);
            *(float4*)&C[row * Nn + bn + tx * 4] = v;
        }
    }
    int head = blockIdx.y;
    float4 av = *(const float4*)&a_src[head * 64 + tx * 4];
    float4 dv = *(const float4*)&a_dst[head * 64 + tx * 4];
#pragma unroll
    for (int i = 0; i < 4; i++) {
        float ps = acc[i][0] * av.x + acc[i][1] * av.y + acc[i][2] * av.z + acc[i][3] * av.w;
        float pd = acc[i][0] * dv.x + acc[i][1] * dv.y + acc[i][2] * dv.z + acc[i][3] * dv.w;
#pragma unroll
        for (int off = 8; off >= 1; off >>= 1) {
            ps += __shfl_xor(ps, off);
            pd += __shfl_xor(pd, off);
        }
        int row = bm + ty * 4 + i;
        if (tx == 0 && row < M) {
            s_sc[row * H + head] = ps;
            d_sc[row * H + head] = pd;
        }
    }
}

// ---------------------------------------------------------------- GAT aggregate
// Wave per node. Pass 1: segment max. Pass 2: LDS-staged ex/idx (wave-private
// slices, no barriers, no shuffles in the hot loop), 4 gathers in flight.
// H=4: whole wave per edge, 4-way j-unroll. H=1: each 16-lane quarter handles
// a different edge per step (4 edges/step), cross-quarter reduce at the end.
template <int H, int C>
__global__ __launch_bounds__(256) void agg_kernel(const float* __restrict__ hbuf,
                                                  const int* __restrict__ row_ptr,
                                                  const int* __restrict__ csr_src,
                                                  const float* __restrict__ s_sc,
                                                  const float* __restrict__ d_sc,
                                                  const float* __restrict__ bias,
                                                  float* __restrict__ out) {
    constexpr int HC = H * C;
    __shared__ int   idxb[4][64];
    __shared__ float exb[4][64][H];
    int w = threadIdx.x >> 6, lane = threadIdx.x & 63;
    int n = blockIdx.x * 4 + w;
    if (n >= NNODES) return;
    int r0 = row_ptr[n], deg = row_ptr[n + 1] - r0;

    float dsc[H];
#pragma unroll
    for (int h = 0; h < H; h++) dsc[h] = d_sc[n * H + h];

    // pass 1: exact segment max
    float mx[H];
#pragma unroll
    for (int h = 0; h < H; h++) mx[h] = -INFINITY;
    for (int i = lane; i < deg; i += 64) {
        int s = csr_src[r0 + i];
#pragma unroll
        for (int h = 0; h < H; h++) {
            float e = s_sc[s * H + h] + dsc[h];
            e = (e >= 0.f) ? e : 0.2f * e;
            mx[h] = fmaxf(mx[h], e);
        }
    }
    for (int off = 32; off >= 1; off >>= 1)
#pragma unroll
        for (int h = 0; h < H; h++) mx[h] = fmaxf(mx[h], __shfl_xor(mx[h], off));

    float denom = 0.f;
    float acc[4] = {0.f, 0.f, 0.f, 0.f};
    for (int base = 0; base < deg; base += 64) {
        int cnt = min(64, deg - base);
        int sl = 0;
        float exl[H];
#pragma unroll
        for (int h = 0; h < H; h++) exl[h] = 0.f;
        if (lane < cnt) {
            sl = csr_src[r0 + base + lane];
#pragma unroll
            for (int h = 0; h < H; h++) {
                float e = s_sc[sl * H + h] + dsc[h];
                e = (e >= 0.f) ? e : 0.2f * e;
                exl[h] = expf(e - mx[h]);
            }
            // pad lanes keep sl=0, exl=0 -> safe gather, zero contribution
        } else {
            sl = 0;
        }
        idxb[w][lane] = sl * HC;
        if constexpr (H == 4) {
            *(float4*)&exb[w][lane][0] = make_float4(exl[0], exl[1], exl[2], exl[3]);
        } else {
            exb[w][lane][0] = exl[0];
        }
        int cnt4 = (cnt + 3) & ~3;
        if constexpr (H == 4) {
            int myh = lane >> 4;                 // head of this lane's channels
            for (int j = 0; j < cnt4; j += 4) {
                int s0 = idxb[w][j + 0], s1 = idxb[w][j + 1];
                int s2 = idxb[w][j + 2], s3 = idxb[w][j + 3];
                float e0 = exb[w][j + 0][myh], e1 = exb[w][j + 1][myh];
                float e2 = exb[w][j + 2][myh], e3 = exb[w][j + 3][myh];
                float4 h0 = *(const float4*)&hbuf[s0 + lane * 4];
                float4 h1 = *(const float4*)&hbuf[s1 + lane * 4];
                float4 h2 = *(const float4*)&hbuf[s2 + lane * 4];
                float4 h3 = *(const float4*)&hbuf[s3 + lane * 4];
                denom += (e0 + e1) + (e2 + e3);
                acc[0] += e0 * h0.x + e1 * h1.x + e2 * h2.x + e3 * h3.x;
                acc[1] += e0 * h0.y + e1 * h1.y + e2 * h2.y + e3 * h3.y;
                acc[2] += e0 * h0.z + e1 * h1.z + e2 * h2.z + e3 * h3.z;
                acc[3] += e0 * h0.w + e1 * h1.w + e2 * h2.w + e3 * h3.w;
            }
        } else {
            int q = lane >> 4, c4 = (lane & 15) * 4;
            for (int j = 0; j < cnt4; j += 4) {
                int sj   = idxb[w][j + q];
                float ej = exb[w][j + q][0];
                float4 hv = *(const float4*)&hbuf[sj + c4];
                denom += ej;
                acc[0] += ej * hv.x; acc[1] += ej * hv.y;
                acc[2] += ej * hv.z; acc[3] += ej * hv.w;
            }
        }
    }
    if constexpr (H == 4) {
        float inv = 1.0f / (denom + 1e-16f);
#pragma unroll
        for (int k = 0; k < 4; k++) {
            float v = acc[k] * inv + bias[lane * 4 + k];
            v = (v > 0.f) ? v : expm1f(v);   // ELU
            out[n * HC + lane * 4 + k] = v;
        }
    } else {
        // reduce across the 4 quarters
#pragma unroll
        for (int off = 16; off <= 32; off <<= 1) {
            denom += __shfl_xor(denom, off);
#pragma unroll
            for (int k = 0; k < 4; k++) acc[k] += __shfl_xor(acc[k], off);
        }
        if (lane < 16) {
            float inv = 1.0f / (denom + 1e-16f);
#pragma unroll
            for (int k = 0; k < 4; k++) {
                float v = acc[k] * inv + bias[lane * 4 + k];
                v = (v > 0.f) ? v : expm1f(v);   // ELU
                out[n * HC + lane * 4 + k] = v;
            }
        }
    }
}

// ---------------------------------------------------------------- batch pool
__global__ __launch_bounds__(256) void pool_kernel(const float* __restrict__ x,
                                                   const int* __restrict__ batch,
                                                   float* __restrict__ pooled,
                                                   float* __restrict__ cntb) {
    int b = blockIdx.x;
    int lo = 0, hi = NNODES;
    while (lo < hi) { int mid = (lo + hi) >> 1; if (batch[mid] < b) lo = mid + 1; else hi = mid; }
    int start = lo;
    hi = NNODES;
    while (lo < hi) { int mid = (lo + hi) >> 1; if (batch[mid] < b + 1) lo = mid + 1; else hi = mid; }
    int end = lo;

    int t = threadIdx.x;
    int c = t & 63, g = t >> 6;
    float s = 0.f;
    for (int n = start + g; n < end; n += 4) s += x[n * 64 + c];
    __shared__ float buf[4][64];
    buf[g][c] = s;
    __syncthreads();
    if (t < 64) {
        pooled[b * 64 + t] = buf[0][t] + buf[1][t] + buf[2][t] + buf[3][t];
        if (t == 0) cntb[b] = (float)(end - start);
    }
}

// ---------------------------------------------------------------- MLP heads
__global__ __launch_bounds__(256) void head_kernel(const float* __restrict__ pL,
                                                   const float* __restrict__ cL,
                                                   const float* __restrict__ pR,
                                                   const float* __restrict__ cR,
                                                   const float* __restrict__ w1a,
                                                   const float* __restrict__ b1a,
                                                   const float* __restrict__ w2a,
                                                   const float* __restrict__ b2a,
                                                   const float* __restrict__ w1b,
                                                   const float* __restrict__ b1b,
                                                   const float* __restrict__ w2b,
                                                   const float* __restrict__ b2b,
                                                   float* __restrict__ out) {
    int b = blockIdx.x;
    int t = threadIdx.x;
    __shared__ float emb[128];
    __shared__ float ph[4][64];
    __shared__ float h1[64];
    if (t < 64)        emb[t] = pL[b * 64 + t] / fmaxf(cL[b], 1.0f);
    else if (t < 128)  emb[t] = pR[b * 64 + (t - 64)] / fmaxf(cR[b], 1.0f);
    __syncthreads();
    int c = t & 63, g = t >> 6;

    {
        float p = 0.f;
#pragma unroll
        for (int k = 0; k < 32; k++) p += emb[g * 32 + k] * w1a[(g * 32 + k) * 64 + c];
        ph[g][c] = p;
        __syncthreads();
        if (t < 64) h1[t] = fmaxf(ph[0][t] + ph[1][t] + ph[2][t] + ph[3][t] + b1a[t], 0.f);
        __syncthreads();
        if (t < 128) {
            int o = t >> 6, lane = t & 63;
            float q = h1[lane] * w2a[lane * 2 + o];
#pragma unroll
            for (int off = 32; off >= 1; off >>= 1) q += __shfl_xor(q, off);
            if (lane == 0) out[b * 2 + o] = q + b2a[o];
        }
        __syncthreads();
    }
    {
        float p = 0.f;
#pragma unroll
        for (int k = 0; k < 32; k++) p += emb[g * 32 + k] * w1b[(g * 32 + k) * 64 + c];
        ph[g][c] = p;
        __syncthreads();
        if (t < 64) h1[t] = fmaxf(ph[0][t] + ph[1][t] + ph[2][t] + ph[3][t] + b1b[t], 0.f);
        __syncthreads();
        if (t < 128) {
            int o = t >> 6, lane = t & 63;
            float q = h1[lane] * w2b[lane * 2 + o];
#pragma unroll
            for (int off = 32; off >= 1; off >>= 1) q += __shfl_xor(q, off);
            if (lane == 0) out[128 + b * 2 + o] = q + b2b[o];
        }
    }
}

// ---------------------------------------------------------------- launcher
extern "C" void kernel_launch(void* const* d_in, const int* in_sizes, int n_in,
                              void* d_out, int out_size, void* d_ws, size_t ws_size,
                              hipStream_t stream) {
    const float* x_left   = (const float*)d_in[0];
    const float* x_right  = (const float*)d_in[1];
    const int*   ei_left  = (const int*)d_in[2];
    const int*   ei_right = (const int*)d_in[3];
    const int*   ba_left  = (const int*)d_in[4];
    const int*   ba_right = (const int*)d_in[5];
    const float* w1  = (const float*)d_in[6];
    const float* as1 = (const float*)d_in[7];
    const float* ad1 = (const float*)d_in[8];
    const float* b1  = (const float*)d_in[9];
    const float* w2  = (const float*)d_in[10];
    const float* as2 = (const float*)d_in[11];
    const float* ad2 = (const float*)d_in[12];
    const float* b2  = (const float*)d_in[13];
    const float* w3  = (const float*)d_in[14];
    const float* as3 = (const float*)d_in[15];
    const float* ad3 = (const float*)d_in[16];
    const float* b3  = (const float*)d_in[17];
    const float* f1w1 = (const float*)d_in[18];
    const float* f1b1 = (const float*)d_in[19];
    const float* f1w2 = (const float*)d_in[20];
    const float* f1b2 = (const float*)d_in[21];
    const float* f2w1 = (const float*)d_in[22];
    const float* f2b1 = (const float*)d_in[23];
    const float* f2w2 = (const float*)d_in[24];
    const float* f2b2 = (const float*)d_in[25];

    char* w = (char*)d_ws;
    auto carve = [&](size_t bytes) {
        void* p = (void*)w;
        w += (bytes + 255) & ~(size_t)255;
        return p;
    };
    float* buf0    = (float*)carve((size_t)NNODES * 256 * 4);
    float* buf1    = (float*)carve((size_t)NNODES * 256 * 4);
    float* s_sc    = (float*)carve((size_t)NNODES * 4 * 4);
    float* d_sc    = (float*)carve((size_t)NNODES * 4 * 4);
    int*   cnt     = (int*)carve((size_t)NNODES * 4);
    int*   row_ptr = (int*)carve((size_t)(NNODES + 1) * 4);
    int*   fillp   = (int*)carve((size_t)NNODES * 4);
    int*   csr     = (int*)carve((size_t)EPRIME * 4);
    float* pooledL = (float*)carve(64 * 64 * 4);
    float* pooledR = (float*)carve(64 * 64 * 4);
    float* cntbL   = (float*)carve(64 * 4);
    float* cntbR   = (float*)carve(64 * 4);

    const int egrid  = (EPRIME + 255) / 256;
    const int ngrid  = (NNODES + 3) / 4;        // wave-per-node kernels
    const int mgrid  = (NNODES + 63) / 64;      // 64-row gemm tiles
    const int mgrid2 = (NNODES + 127) / 128;    // 128-row gemm tiles

    for (int side = 0; side < 2; side++) {
        const float* x_in  = side ? x_right  : x_left;
        const int*   ei    = side ? ei_right : ei_left;
        const int*   batch = side ? ba_right : ba_left;
        float* pooled = side ? pooledR : pooledL;
        float* cntb   = side ? cntbR   : cntbL;

        // CSR by dst (shared across the 3 layers)
        hipMemsetAsync(cnt, 0, (size_t)NNODES * 4, stream);
        count_kernel<<<egrid, 256, 0, stream>>>(ei, cnt);
        scan_kernel<<<1, 1024, 0, stream>>>(cnt, row_ptr, fillp);
        fill_kernel<<<egrid, 256, 0, stream>>>(ei, fillp, csr);

        // layer 1: x[N,128] @ w1[128,256] + fused scores
        gemm128x64_kernel<<<dim3(mgrid2, 4), 256, 0, stream>>>(x_in, w1, buf0, NNODES, 128, 256,
                                                               as1, ad1, s_sc, d_sc, 4);
        agg_kernel<4, 64><<<ngrid, 256, 0, stream>>>(buf0, row_ptr, csr, s_sc, d_sc, b1, buf1);

        // layer 2: buf1[N,256] @ w2[256,256] + fused scores
        gemm128x64_kernel<<<dim3(mgrid2, 4), 256, 0, stream>>>(buf1, w2, buf0, NNODES, 256, 256,
                                                               as2, ad2, s_sc, d_sc, 4);
        agg_kernel<4, 64><<<ngrid, 256, 0, stream>>>(buf0, row_ptr, csr, s_sc, d_sc, b2, buf1);

        // layer 3: buf1[N,256] @ w3[256,64], single head + fused scores
        gemm_kernel<<<dim3(mgrid, 1), 256, 0, stream>>>(buf1, w3, buf0, NNODES, 256, 64,
                                                        as3, ad3, s_sc, d_sc, 1);
        agg_kernel<1, 64><<<ngrid, 256, 0, stream>>>(buf0, row_ptr, csr, s_sc, d_sc, b3, buf1);

        // batch mean-pool
        pool_kernel<<<NBATCH, 256, 0, stream>>>(buf1, batch, pooled, cntb);
    }

    head_kernel<<<NBATCH, 256, 0, stream>>>(pooledL, cntbL, pooledR, cntbR,
                                            f1w1, f1b1, f1w2, f1b2,
                                            f2w1, f2b1, f2w2, f2b2,
                                            (float*)d_out);
}